// Round 5
// baseline (549.475 us; speedup 1.0000x reference)
//
#include <hip/hip_runtime.h>
#include <hip/hip_fp16.h>
#include <math.h>

constexpr int   NN     = 50000;   // nodes
constexpr int   IN_DIM = 128;
constexpr int   HID    = 64;
constexpr int   NE     = 800000;  // edges
constexpr float ALPHA  = 0.1520f;
constexpr float BETA   = 0.7900f;

constexpr int RSH = 7;                      // rows per bucket = 128
constexpr int RPB = 1 << RSH;
constexpr int NB  = (NN + RPB - 1) / RPB;   // 391 buckets
constexpr int NBP = 512;                    // padded scan width
constexpr int CH  = 4096;                   // edges per binfill block
constexpr int NCH = (NE + CH - 1) / CH;     // 196

// ---------------- per-row degree (atomic int) ----------------
__global__ void k_count(const int* __restrict__ row, int* __restrict__ ec) {
    int e = blockIdx.x * blockDim.x + threadIdx.x;
    if (e < NE) atomicAdd(&ec[row[e]], 1);
}

// ---------------- dinv + per-bucket edge counts from ec ----------------
__global__ void k_bsum_dinv(const int* __restrict__ ec, float* __restrict__ dinv,
                            int* __restrict__ bhist) {
    int b = blockIdx.x, t = threadIdx.x;  // 128 threads
    int r = (b << RSH) + t;
    int v = (r < NN) ? ec[r] : 0;
    if (r < NN) dinv[r] = rsqrtf((float)(v + 1));   // self loop included
#pragma unroll
    for (int d = 32; d >= 1; d >>= 1) v += __shfl_xor(v, d);
    __shared__ int ws[2];
    if ((t & 63) == 0) ws[t >> 6] = v;
    __syncthreads();
    if (t == 0) bhist[b] = ws[0] + ws[1];
}

// ---------------- exclusive scan of bucket counts ----------------
__global__ void k_bscan(const int* __restrict__ bhist, int* __restrict__ boffs,
                        int* __restrict__ bcur) {
    __shared__ int s[NBP];
    int t = threadIdx.x;  // 256
    s[t]       = (t < NB) ? bhist[t] : 0;
    s[t + 256] = (t + 256 < NB) ? bhist[t + 256] : 0;
    __syncthreads();
    for (int d = 1; d < NBP; d <<= 1) {
        int v0 = (t >= d) ? s[t - d] : 0;
        int v1 = (t + 256 >= d) ? s[t + 256 - d] : 0;
        __syncthreads();
        s[t] += v0;
        s[t + 256] += v1;
        __syncthreads();
    }
    if (t < NB)       { int e = s[t] - bhist[t];             boffs[t] = e;       bcur[t] = e; }
    if (t + 256 < NB) { int e = s[t + 256] - bhist[t + 256]; boffs[t + 256] = e; bcur[t + 256] = e; }
    if (t == 0) boffs[NB] = NE;
}

// ---------------- binned fill: bucket-sorted packed edges, coalesced runs ----------------
__global__ __launch_bounds__(256) void k_binfill(const int* __restrict__ row,
                                                 const int* __restrict__ col,
                                                 int* __restrict__ bcur,
                                                 unsigned int* __restrict__ bedge) {
    __shared__ int hist[NBP];
    __shared__ int scn[NBP];
    __shared__ int ebase[NB];
    __shared__ int gbase[NB];
    __shared__ int lcur[NB];
    __shared__ unsigned int pk[CH];
    __shared__ int gof[CH];

    int t = threadIdx.x;
    int e0 = blockIdx.x * CH;
    int rw[16], cl[16];
#pragma unroll
    for (int i = 0; i < 16; ++i) {
        int e = e0 + i * 256 + t;
        if (e < NE) { rw[i] = row[e]; cl[i] = col[e]; } else rw[i] = -1;
    }
    for (int i = t; i < NBP; i += 256) hist[i] = 0;
    __syncthreads();
#pragma unroll
    for (int i = 0; i < 16; ++i)
        if (rw[i] >= 0) atomicAdd(&hist[rw[i] >> RSH], 1);
    __syncthreads();
    scn[t] = hist[t];
    scn[t + 256] = hist[t + 256];
    __syncthreads();
    for (int d = 1; d < NBP; d <<= 1) {
        int v0 = (t >= d) ? scn[t - d] : 0;
        int v1 = (t + 256 >= d) ? scn[t + 256 - d] : 0;
        __syncthreads();
        scn[t] += v0;
        scn[t + 256] += v1;
        __syncthreads();
    }
    for (int b = t; b < NB; b += 256) {
        int h  = hist[b];
        int eb = scn[b] - h;          // local exclusive base
        ebase[b] = eb;
        lcur[b]  = eb;
        gbase[b] = h ? atomicAdd(&bcur[b], h) : 0;
    }
    __syncthreads();
#pragma unroll
    for (int i = 0; i < 16; ++i) {
        if (rw[i] >= 0) {
            int b = rw[i] >> RSH;
            int s = atomicAdd(&lcur[b], 1);
            pk[s]  = ((unsigned int)(rw[i] & (RPB - 1)) << 17) | (unsigned int)cl[i];
            gof[s] = gbase[b] + (s - ebase[b]);
        }
    }
    __syncthreads();
    int nval = min(CH, NE - e0);
    for (int s = t; s < nval; s += 256) bedge[gof[s]] = pk[s];
}

// ---------------- GEMM1: h1s = fp16( dinv[n] * (feat @ W1) ) ----------------
__global__ __launch_bounds__(256) void k_gemm1(const float* __restrict__ feat,
                                               const float* __restrict__ W1,
                                               const float* __restrict__ dinv,
                                               __half* __restrict__ h1s) {
    __shared__ float sW[IN_DIM * HID];
    __shared__ float sF[16][IN_DIM];
    int t = threadIdx.x;

    const float4* W4  = (const float4*)W1;
    float4*       sW4 = (float4*)sW;
#pragma unroll
    for (int i = 0; i < 8; ++i) sW4[t + i * 256] = W4[t + i * 256];

    int n0 = blockIdx.x * 16;
    const float4* F4  = (const float4*)(feat + (size_t)n0 * IN_DIM);
    float4*       sF4 = (float4*)&sF[0][0];
    sF4[t]       = F4[t];
    sF4[t + 256] = F4[t + 256];
    __syncthreads();

    int c = t & 63;
    int g = t >> 6;
    float acc[4] = {0.f, 0.f, 0.f, 0.f};
    for (int k = 0; k < IN_DIM; ++k) {
        float w = sW[k * HID + c];
#pragma unroll
        for (int i = 0; i < 4; ++i) acc[i] += sF[g * 4 + i][k] * w;
    }
#pragma unroll
    for (int i = 0; i < 4; ++i) {
        int n = n0 + g * 4 + i;
        h1s[(size_t)n * HID + c] = __float2half(acc[i] * dinv[n]);
    }
}

// ---------------- bucketed layer-1 aggregation + b1 + relu + W2 -> h2s ----------------
// one block per bucket; 8 waves stream edges, LDS fp32 accumulator (ds_add_f32)
__global__ __launch_bounds__(512) void k_bagg1(const int* __restrict__ boffs,
                                               const unsigned int* __restrict__ bedge,
                                               const float* __restrict__ dinv,
                                               const __half* __restrict__ h1s,
                                               const float* __restrict__ b1,
                                               const float* __restrict__ W2,
                                               float* __restrict__ h2s) {
    __shared__ float acc[RPB * HID];  // 32 KB
    int t = threadIdx.x;
    int b = blockIdx.x;
    for (int i = t; i < RPB * HID; i += 512) acc[i] = 0.f;
    __syncthreads();

    int beg = boffs[b], end = boffs[b + 1];
    int wid = t >> 6, lane = t & 63;
    int k = beg + (wid << 2);
    for (; k + 3 < end; k += 32) {
        unsigned int m0 = bedge[k], m1 = bedge[k + 1], m2 = bedge[k + 2], m3 = bedge[k + 3];
        float v0 = __half2float(h1s[(size_t)(m0 & 0x1FFFFu) * HID + lane]);
        float v1 = __half2float(h1s[(size_t)(m1 & 0x1FFFFu) * HID + lane]);
        float v2 = __half2float(h1s[(size_t)(m2 & 0x1FFFFu) * HID + lane]);
        float v3 = __half2float(h1s[(size_t)(m3 & 0x1FFFFu) * HID + lane]);
        atomicAdd(&acc[((m0 >> 17) << 6) + lane], v0);
        atomicAdd(&acc[((m1 >> 17) << 6) + lane], v1);
        atomicAdd(&acc[((m2 >> 17) << 6) + lane], v2);
        atomicAdd(&acc[((m3 >> 17) << 6) + lane], v3);
    }
    for (; k < end; ++k) {  // at most one wave lands here (partial last group)
        unsigned int m = bedge[k];
        float v = __half2float(h1s[(size_t)(m & 0x1FFFFu) * HID + lane]);
        atomicAdd(&acc[((m >> 17) << 6) + lane], v);
    }
    __syncthreads();

    int nbase = b << RSH;
    for (int r = wid; r < RPB; r += 8) {
        int n = nbase + r;
        if (n >= NN) break;
        float di = dinv[n];
        float a = acc[(r << 6) + lane];
        a = di * (a + __half2float(h1s[(size_t)n * HID + lane])) + b1[lane];
        a = fmaxf(a, 0.f);
        float p0 = a * W2[lane * 2 + 0];
        float p1 = a * W2[lane * 2 + 1];
#pragma unroll
        for (int d = 32; d >= 1; d >>= 1) {
            p0 += __shfl_xor(p0, d);
            p1 += __shfl_xor(p1, d);
        }
        if (lane == 0) {
            h2s[(size_t)n * 2 + 0] = di * p0;
            h2s[(size_t)n * 2 + 1] = di * p1;
        }
    }
}

// ---------------- layer-2 scatter (atomic, 8B/edge) ----------------
__global__ void k_scat2(const int* __restrict__ row, const int* __restrict__ col,
                        const float* __restrict__ h2s, float* __restrict__ agg2) {
    int e = blockIdx.x * blockDim.x + threadIdx.x;
    if (e >= NE) return;
    const float2* h22 = (const float2*)h2s;
    float2 v = h22[col[e]];
    int r = row[e];
    atomicAdd(&agg2[r * 2 + 0], v.x);
    atomicAdd(&agg2[r * 2 + 1], v.y);
}

__global__ void k_emb(const float* __restrict__ agg2, const float* __restrict__ h2s,
                      const float* __restrict__ dinv, const float* __restrict__ b2,
                      float* __restrict__ emb) {
    int n = blockIdx.x * blockDim.x + threadIdx.x;
    if (n >= NN) return;
    float di = dinv[n];
    emb[n * 2 + 0] = di * (agg2[n * 2 + 0] + h2s[n * 2 + 0]) + b2[0];
    emb[n * 2 + 1] = di * (agg2[n * 2 + 1] + h2s[n * 2 + 1]) + b2[1];
}

// ---------------- q = 1/(1 + alpha * d^(2*beta)) ----------------
__global__ void k_q(const int* __restrict__ pr, const int* __restrict__ pc,
                    const int* __restrict__ nr, const int* __restrict__ nc,
                    const float* __restrict__ emb, float* __restrict__ q) {
    int e = blockIdx.x * blockDim.x + threadIdx.x;
    if (e >= 2 * NE) return;
    int a, b;
    if (e < NE) { a = pr[e]; b = pc[e]; }
    else        { a = nr[e - NE]; b = nc[e - NE]; }
    const float2* e2 = (const float2*)emb;
    float2 A = e2[a], B = e2[b];
    float dx = A.x - B.x, dy = A.y - B.y;
    float d = sqrtf(dx * dx + dy * dy + 1e-12f);
    float p = exp2f(2.0f * BETA * log2f(d));
    q[e] = 1.0f / (1.0f + ALPHA * p);
}

extern "C" void kernel_launch(void* const* d_in, const int* in_sizes, int n_in,
                              void* d_out, int out_size, void* d_ws, size_t ws_size,
                              hipStream_t stream) {
    const float* feat = (const float*)d_in[0];
    const float* W1   = (const float*)d_in[1];
    const float* b1   = (const float*)d_in[2];
    const float* W2   = (const float*)d_in[3];
    const float* b2   = (const float*)d_in[4];
    const int*   ei   = (const int*)d_in[5];
    const int*   nrw  = (const int*)d_in[6];
    const int*   ncl  = (const int*)d_in[7];
    const int* row = ei;
    const int* col = ei + NE;

    char* cur = (char*)d_ws;
    auto alloc = [&](size_t bytes) -> char* {
        char* p = cur;
        cur += (bytes + 255) & ~(size_t)255;
        return p;
    };
    int*          ec    = (int*)alloc(sizeof(int) * NN);
    float*        dinv  = (float*)alloc(sizeof(float) * NN);
    int*          bhist = (int*)alloc(sizeof(int) * NB);
    int*          boffs = (int*)alloc(sizeof(int) * (NB + 1));
    int*          bcur  = (int*)alloc(sizeof(int) * NB);
    unsigned int* bedge = (unsigned int*)alloc(sizeof(unsigned int) * NE);
    float*        h2s   = (float*)alloc(sizeof(float) * (size_t)NN * 2);
    float*        agg2  = (float*)alloc(sizeof(float) * (size_t)NN * 2);
    __half*       h1s   = (__half*)alloc(sizeof(__half) * (size_t)NN * HID);

    float* emb = (float*)d_out;
    float* q   = (float*)d_out + (size_t)NN * 2;

    hipError_t _e;
    _e = hipMemsetAsync(ec, 0, sizeof(int) * NN, stream);            (void)_e;
    _e = hipMemsetAsync(agg2, 0, sizeof(float) * (size_t)NN * 2, stream); (void)_e;

    k_count<<<(NE + 255) / 256, 256, 0, stream>>>(row, ec);
    k_bsum_dinv<<<NB, 128, 0, stream>>>(ec, dinv, bhist);
    k_bscan<<<1, 256, 0, stream>>>(bhist, boffs, bcur);
    k_binfill<<<NCH, 256, 0, stream>>>(row, col, bcur, bedge);

    k_gemm1<<<NN / 16, 256, 0, stream>>>(feat, W1, dinv, h1s);

    k_bagg1<<<NB, 512, 0, stream>>>(boffs, bedge, dinv, h1s, b1, W2, h2s);

    k_scat2<<<(NE + 255) / 256, 256, 0, stream>>>(row, col, h2s, agg2);
    k_emb<<<(NN + 255) / 256, 256, 0, stream>>>(agg2, h2s, dinv, b2, emb);

    k_q<<<(2 * NE + 255) / 256, 256, 0, stream>>>(row, col, nrw, ncl, emb, q);
}

// Round 6
// 236.400 us; speedup vs baseline: 2.3243x; 2.3243x over previous
//
#include <hip/hip_runtime.h>
#include <hip/hip_fp16.h>
#include <math.h>

constexpr int   NN     = 50000;   // nodes
constexpr int   IN_DIM = 128;
constexpr int   HID    = 64;
constexpr int   NE     = 800000;  // edges
constexpr float ALPHA  = 0.1520f;
constexpr float BETA   = 0.7900f;

constexpr int SCAN_BLOCKS = (NN + 255) / 256;  // 196

constexpr int RSH = 7;                      // rows per bucket = 128
constexpr int RPB = 1 << RSH;
constexpr int NB  = (NN + RPB - 1) / RPB;   // 391 buckets
constexpr int NBP = 512;                    // padded width
constexpr int CH  = 4096;                   // edges per binfill block
constexpr int NCH = (NE + CH - 1) / CH;     // 196
constexpr int CAP = 10240;                  // csrfill LDS buffer entries (40 KB)

// ---------------- per-row degree ----------------
__global__ void k_count(const int* __restrict__ row, int* __restrict__ ec) {
    int e = blockIdx.x * blockDim.x + threadIdx.x;
    if (e < NE) atomicAdd(&ec[row[e]], 1);
}

// ---------------- scan phase 1 (+ dinv fused) ----------------
__global__ void k_scan1(const int* __restrict__ ec, int* __restrict__ loc,
                        int* __restrict__ part, float* __restrict__ dinv) {
    __shared__ int s[256];
    int t = threadIdx.x;
    int i = blockIdx.x * 256 + t;
    int v = (i < NN) ? ec[i] : 0;
    if (i < NN) dinv[i] = rsqrtf((float)(v + 1));  // self loop included
    s[t] = v;
    __syncthreads();
    for (int d = 1; d < 256; d <<= 1) {
        int u = (t >= d) ? s[t - d] : 0;
        __syncthreads();
        s[t] += u;
        __syncthreads();
    }
    if (i < NN) loc[i] = s[t] - v;
    if (t == 255) part[blockIdx.x] = s[255];
}

__global__ void k_scan2(int* __restrict__ part) {  // single block of 256
    __shared__ int s[256];
    int t = threadIdx.x;
    int v = (t < SCAN_BLOCKS) ? part[t] : 0;
    s[t] = v;
    __syncthreads();
    for (int d = 1; d < 256; d <<= 1) {
        int u = (t >= d) ? s[t - d] : 0;
        __syncthreads();
        s[t] += u;
        __syncthreads();
    }
    if (t < SCAN_BLOCKS) part[t] = s[t] - v;
}

// offs + per-bucket cursors (bcur[b] = offs[b*128])
__global__ void k_scan3(const int* __restrict__ loc, const int* __restrict__ part,
                        int* __restrict__ offs, int* __restrict__ bcur) {
    int i = blockIdx.x * blockDim.x + threadIdx.x;
    if (i < NN) {
        int o = loc[i] + part[i >> 8];
        offs[i] = o;
        if ((i & (RPB - 1)) == 0) bcur[i >> RSH] = o;
    }
    if (i == 0) offs[NN] = NE;
}

// ---------------- phase 1: bucket-sort edges, coalesced run writes ----------------
__global__ __launch_bounds__(256) void k_binfill(const int* __restrict__ row,
                                                 const int* __restrict__ col,
                                                 int* __restrict__ bcur,
                                                 unsigned int* __restrict__ bedge) {
    __shared__ int hist[NBP];
    __shared__ int scn[NBP];
    __shared__ int ebase[NB];
    __shared__ int gbase[NB];
    __shared__ int lcur[NB];
    __shared__ unsigned int pk[CH];
    __shared__ int gof[CH];

    int t = threadIdx.x;
    int e0 = blockIdx.x * CH;
    int rw[16], cl[16];
#pragma unroll
    for (int i = 0; i < 16; ++i) {
        int e = e0 + i * 256 + t;
        if (e < NE) { rw[i] = row[e]; cl[i] = col[e]; } else rw[i] = -1;
    }
    for (int i = t; i < NBP; i += 256) hist[i] = 0;
    __syncthreads();
#pragma unroll
    for (int i = 0; i < 16; ++i)
        if (rw[i] >= 0) atomicAdd(&hist[rw[i] >> RSH], 1);
    __syncthreads();
    scn[t] = hist[t];
    scn[t + 256] = hist[t + 256];
    __syncthreads();
    for (int d = 1; d < NBP; d <<= 1) {
        int v0 = (t >= d) ? scn[t - d] : 0;
        int v1 = (t + 256 >= d) ? scn[t + 256 - d] : 0;
        __syncthreads();
        scn[t] += v0;
        scn[t + 256] += v1;
        __syncthreads();
    }
    for (int b = t; b < NB; b += 256) {
        int h  = hist[b];
        int eb = scn[b] - h;
        ebase[b] = eb;
        lcur[b]  = eb;
        gbase[b] = h ? atomicAdd(&bcur[b], h) : 0;
    }
    __syncthreads();
#pragma unroll
    for (int i = 0; i < 16; ++i) {
        if (rw[i] >= 0) {
            int b = rw[i] >> RSH;
            int s = atomicAdd(&lcur[b], 1);
            pk[s]  = ((unsigned int)(rw[i] & (RPB - 1)) << 17) | (unsigned int)cl[i];
            gof[s] = gbase[b] + (s - ebase[b]);
        }
    }
    __syncthreads();
    int nval = min(CH, NE - e0);
    for (int s = t; s < nval; s += 256) bedge[gof[s]] = pk[s];
}

// ---------------- phase 2: bucket -> per-node CSR, all coalesced ----------------
__global__ __launch_bounds__(256) void k_csrfill(const unsigned int* __restrict__ bedge,
                                                 const int* __restrict__ offs,
                                                 int* __restrict__ scol) {
    __shared__ int cur[RPB];
    __shared__ int buf[CAP];
    int b = blockIdx.x, t = threadIdx.x;
    int nbase = b << RSH;
    int nend  = min(nbase + RPB, NN);
    int beg = offs[nbase];
    int end = offs[nend];
    int cnt = end - beg;
    if (t < RPB) cur[t] = (nbase + t < NN) ? (offs[nbase + t] - beg) : 0;
    __syncthreads();
    if (cnt <= CAP) {
        for (int i = t; i < cnt; i += 256) {
            unsigned int m = bedge[beg + i];
            int s = atomicAdd(&cur[m >> 17], 1);
            buf[s] = (int)(m & 0x1FFFFu);
        }
        __syncthreads();
        for (int i = t; i < cnt; i += 256) scol[beg + i] = buf[i];
    } else {  // safety fallback (never hit at these sizes)
        for (int i = t; i < cnt; i += 256) {
            unsigned int m = bedge[beg + i];
            int s = atomicAdd(&cur[m >> 17], 1);
            scol[beg + s] = (int)(m & 0x1FFFFu);
        }
    }
}

// ---------------- GEMM1: h1s = fp16( dinv[n] * (feat @ W1) ) ----------------
__global__ __launch_bounds__(256) void k_gemm1(const float* __restrict__ feat,
                                               const float* __restrict__ W1,
                                               const float* __restrict__ dinv,
                                               __half* __restrict__ h1s) {
    __shared__ float sW[IN_DIM * HID];
    __shared__ float sF[16][IN_DIM];
    int t = threadIdx.x;

    const float4* W4  = (const float4*)W1;
    float4*       sW4 = (float4*)sW;
#pragma unroll
    for (int i = 0; i < 8; ++i) sW4[t + i * 256] = W4[t + i * 256];

    int n0 = blockIdx.x * 16;
    const float4* F4  = (const float4*)(feat + (size_t)n0 * IN_DIM);
    float4*       sF4 = (float4*)&sF[0][0];
    sF4[t]       = F4[t];
    sF4[t + 256] = F4[t + 256];
    __syncthreads();

    int c = t & 63;
    int g = t >> 6;
    float acc[4] = {0.f, 0.f, 0.f, 0.f};
    for (int k = 0; k < IN_DIM; ++k) {
        float w = sW[k * HID + c];
#pragma unroll
        for (int i = 0; i < 4; ++i) acc[i] += sF[g * 4 + i][k] * w;
    }
#pragma unroll
    for (int i = 0; i < 4; ++i) {
        int n = n0 + g * 4 + i;
        h1s[(size_t)n * HID + c] = __float2half(acc[i] * dinv[n]);
    }
}

// ---------------- fused: agg1(gather) + b1 + relu + @W2 -> h2s (pre-scaled) ----------------
__global__ __launch_bounds__(256) void k_agg1(const int* __restrict__ offs,
                                              const int* __restrict__ scol,
                                              const float* __restrict__ dinv,
                                              const __half* __restrict__ h1s,
                                              const float* __restrict__ b1,
                                              const float* __restrict__ W2,
                                              float* __restrict__ h2s) {
    int n    = blockIdx.x * 4 + (threadIdx.x >> 6);
    int lane = threadIdx.x & 63;
    if (n >= NN) return;
    int beg = offs[n], end = offs[n + 1];
    float acc = 0.f;
    int k = beg;
    for (; k + 3 < end; k += 4) {
        int c0 = scol[k], c1 = scol[k + 1], c2 = scol[k + 2], c3 = scol[k + 3];
        float v0 = __half2float(h1s[(size_t)c0 * HID + lane]);
        float v1 = __half2float(h1s[(size_t)c1 * HID + lane]);
        float v2 = __half2float(h1s[(size_t)c2 * HID + lane]);
        float v3 = __half2float(h1s[(size_t)c3 * HID + lane]);
        acc += (v0 + v1) + (v2 + v3);
    }
    for (; k < end; ++k)
        acc += __half2float(h1s[(size_t)scol[k] * HID + lane]);

    float di = dinv[n];
    acc = di * (acc + __half2float(h1s[(size_t)n * HID + lane]));  // + self loop
    acc += b1[lane];
    acc = fmaxf(acc, 0.f);
    float p0 = acc * W2[lane * 2 + 0];
    float p1 = acc * W2[lane * 2 + 1];
#pragma unroll
    for (int d = 32; d >= 1; d >>= 1) {
        p0 += __shfl_xor(p0, d);
        p1 += __shfl_xor(p1, d);
    }
    if (lane == 0) {
        h2s[(size_t)n * 2 + 0] = di * p0;
        h2s[(size_t)n * 2 + 1] = di * p1;
    }
}

// ---------------- layer-2 scatter (atomic, 8B/edge, L2-resident dst) ----------------
__global__ void k_scat2(const int* __restrict__ row, const int* __restrict__ col,
                        const float* __restrict__ h2s, float* __restrict__ agg2) {
    int e = blockIdx.x * blockDim.x + threadIdx.x;
    if (e >= NE) return;
    const float2* h22 = (const float2*)h2s;
    float2 v = h22[col[e]];
    int r = row[e];
    atomicAdd(&agg2[r * 2 + 0], v.x);
    atomicAdd(&agg2[r * 2 + 1], v.y);
}

__global__ void k_emb(const float* __restrict__ agg2, const float* __restrict__ h2s,
                      const float* __restrict__ dinv, const float* __restrict__ b2,
                      float* __restrict__ emb) {
    int n = blockIdx.x * blockDim.x + threadIdx.x;
    if (n >= NN) return;
    float di = dinv[n];
    emb[n * 2 + 0] = di * (agg2[n * 2 + 0] + h2s[n * 2 + 0]) + b2[0];
    emb[n * 2 + 1] = di * (agg2[n * 2 + 1] + h2s[n * 2 + 1]) + b2[1];
}

// ---------------- q = 1/(1 + alpha * d^(2*beta)) ----------------
__global__ void k_q(const int* __restrict__ pr, const int* __restrict__ pc,
                    const int* __restrict__ nr, const int* __restrict__ nc,
                    const float* __restrict__ emb, float* __restrict__ q) {
    int e = blockIdx.x * blockDim.x + threadIdx.x;
    if (e >= 2 * NE) return;
    int a, b;
    if (e < NE) { a = pr[e]; b = pc[e]; }
    else        { a = nr[e - NE]; b = nc[e - NE]; }
    const float2* e2 = (const float2*)emb;
    float2 A = e2[a], B = e2[b];
    float dx = A.x - B.x, dy = A.y - B.y;
    float d = sqrtf(dx * dx + dy * dy + 1e-12f);
    float p = exp2f(2.0f * BETA * log2f(d));
    q[e] = 1.0f / (1.0f + ALPHA * p);
}

extern "C" void kernel_launch(void* const* d_in, const int* in_sizes, int n_in,
                              void* d_out, int out_size, void* d_ws, size_t ws_size,
                              hipStream_t stream) {
    const float* feat = (const float*)d_in[0];
    const float* W1   = (const float*)d_in[1];
    const float* b1   = (const float*)d_in[2];
    const float* W2   = (const float*)d_in[3];
    const float* b2   = (const float*)d_in[4];
    const int*   ei   = (const int*)d_in[5];
    const int*   nrw  = (const int*)d_in[6];
    const int*   ncl  = (const int*)d_in[7];
    const int* row = ei;
    const int* col = ei + NE;

    char* cur = (char*)d_ws;
    auto alloc = [&](size_t bytes) -> char* {
        char* p = cur;
        cur += (bytes + 255) & ~(size_t)255;
        return p;
    };
    int*          ec    = (int*)alloc(sizeof(int) * NN);
    int*          loc   = (int*)alloc(sizeof(int) * NN);
    int*          part  = (int*)alloc(sizeof(int) * 256);
    int*          offs  = (int*)alloc(sizeof(int) * (NN + 1));
    int*          bcur  = (int*)alloc(sizeof(int) * NB);
    float*        dinv  = (float*)alloc(sizeof(float) * NN);
    unsigned int* bedge = (unsigned int*)alloc(sizeof(unsigned int) * NE);
    int*          scol  = (int*)alloc(sizeof(int) * NE);
    float*        h2s   = (float*)alloc(sizeof(float) * (size_t)NN * 2);
    float*        agg2  = (float*)alloc(sizeof(float) * (size_t)NN * 2);
    __half*       h1s   = (__half*)alloc(sizeof(__half) * (size_t)NN * HID);

    float* emb = (float*)d_out;
    float* q   = (float*)d_out + (size_t)NN * 2;

    hipError_t _e;
    _e = hipMemsetAsync(ec, 0, sizeof(int) * NN, stream);                 (void)_e;
    _e = hipMemsetAsync(agg2, 0, sizeof(float) * (size_t)NN * 2, stream); (void)_e;

    k_count<<<(NE + 255) / 256, 256, 0, stream>>>(row, ec);
    k_scan1<<<SCAN_BLOCKS, 256, 0, stream>>>(ec, loc, part, dinv);
    k_scan2<<<1, 256, 0, stream>>>(part);
    k_scan3<<<SCAN_BLOCKS, 256, 0, stream>>>(loc, part, offs, bcur);

    k_binfill<<<NCH, 256, 0, stream>>>(row, col, bcur, bedge);
    k_csrfill<<<NB, 256, 0, stream>>>(bedge, offs, scol);

    k_gemm1<<<NN / 16, 256, 0, stream>>>(feat, W1, dinv, h1s);

    k_agg1<<<(NN + 3) / 4, 256, 0, stream>>>(offs, scol, dinv, h1s, b1, W2, h2s);

    k_scat2<<<(NE + 255) / 256, 256, 0, stream>>>(row, col, h2s, agg2);
    k_emb<<<(NN + 255) / 256, 256, 0, stream>>>(agg2, h2s, dinv, b2, emb);

    k_q<<<(2 * NE + 255) / 256, 256, 0, stream>>>(row, col, nrw, ncl, emb, q);
}

// Round 7
// 128.299 us; speedup vs baseline: 4.2828x; 1.8426x over previous
//
#include <hip/hip_runtime.h>
#include <hip/hip_fp16.h>
#include <math.h>

constexpr int   NN     = 50000;   // nodes
constexpr int   IN_DIM = 128;
constexpr int   HID    = 64;
constexpr int   NE     = 800000;  // edges
constexpr float ALPHA  = 0.1520f;
constexpr float BETA   = 0.7900f;

constexpr int RSH = 7;                      // rows per bucket = 128
constexpr int RPB = 1 << RSH;
constexpr int NB  = (NN + RPB - 1) / RPB;   // 391 buckets
constexpr int NBP = 512;                    // padded width
constexpr int CH  = 4096;                   // edges per chunk block
constexpr int NCH = (NE + CH - 1) / CH;     // 196
constexpr int CAP = 4096;                   // per-bucket LDS edge capacity
                                            // (mean 2046, Poisson std ~45 -> safe)

// ---------------- per-bucket histogram (LDS-privatized) ----------------
__global__ __launch_bounds__(256) void k_bhist(const int* __restrict__ row,
                                               int* __restrict__ bhist) {
    __shared__ int h[NBP];
    int t = threadIdx.x;
    for (int i = t; i < NBP; i += 256) h[i] = 0;
    __syncthreads();
    int e0 = blockIdx.x * CH;
#pragma unroll
    for (int i = 0; i < 16; ++i) {
        int e = e0 + i * 256 + t;
        if (e < NE) atomicAdd(&h[row[e] >> RSH], 1);
    }
    __syncthreads();
    for (int b = t; b < NB; b += 256)
        if (h[b]) atomicAdd(&bhist[b], h[b]);
}

// ---------------- exclusive scan of bucket counts ----------------
__global__ void k_bscan(const int* __restrict__ bhist, int* __restrict__ boffs,
                        int* __restrict__ bcur) {
    __shared__ int s[NBP];
    int t = threadIdx.x;  // 256
    s[t]       = (t < NB) ? bhist[t] : 0;
    s[t + 256] = (t + 256 < NB) ? bhist[t + 256] : 0;
    __syncthreads();
    for (int d = 1; d < NBP; d <<= 1) {
        int v0 = (t >= d) ? s[t - d] : 0;
        int v1 = (t + 256 >= d) ? s[t + 256 - d] : 0;
        __syncthreads();
        s[t] += v0;
        s[t + 256] += v1;
        __syncthreads();
    }
    if (t < NB)       { int e = s[t] - bhist[t];             boffs[t] = e;       bcur[t] = e; }
    if (t + 256 < NB) { int e = s[t + 256] - bhist[t + 256]; boffs[t + 256] = e; bcur[t + 256] = e; }
    if (t == 0) boffs[NB] = NE;
}

// ---------------- bucket-sort edges into packed words, coalesced runs ----------------
__global__ __launch_bounds__(256) void k_binfill(const int* __restrict__ row,
                                                 const int* __restrict__ col,
                                                 int* __restrict__ bcur,
                                                 unsigned int* __restrict__ bedge) {
    __shared__ int hist[NBP];
    __shared__ int scn[NBP];
    __shared__ int ebase[NB];
    __shared__ int gbase[NB];
    __shared__ int lcur[NB];
    __shared__ unsigned int pk[CH];
    __shared__ int gof[CH];

    int t = threadIdx.x;
    int e0 = blockIdx.x * CH;
    int rw[16], cl[16];
#pragma unroll
    for (int i = 0; i < 16; ++i) {
        int e = e0 + i * 256 + t;
        if (e < NE) { rw[i] = row[e]; cl[i] = col[e]; } else rw[i] = -1;
    }
    for (int i = t; i < NBP; i += 256) hist[i] = 0;
    __syncthreads();
#pragma unroll
    for (int i = 0; i < 16; ++i)
        if (rw[i] >= 0) atomicAdd(&hist[rw[i] >> RSH], 1);
    __syncthreads();
    scn[t] = hist[t];
    scn[t + 256] = hist[t + 256];
    __syncthreads();
    for (int d = 1; d < NBP; d <<= 1) {
        int v0 = (t >= d) ? scn[t - d] : 0;
        int v1 = (t + 256 >= d) ? scn[t + 256 - d] : 0;
        __syncthreads();
        scn[t] += v0;
        scn[t + 256] += v1;
        __syncthreads();
    }
    for (int b = t; b < NB; b += 256) {
        int h  = hist[b];
        int eb = scn[b] - h;
        ebase[b] = eb;
        lcur[b]  = eb;
        gbase[b] = h ? atomicAdd(&bcur[b], h) : 0;
    }
    __syncthreads();
#pragma unroll
    for (int i = 0; i < 16; ++i) {
        if (rw[i] >= 0) {
            int b = rw[i] >> RSH;
            int s = atomicAdd(&lcur[b], 1);
            pk[s]  = ((unsigned int)(rw[i] & (RPB - 1)) << 17) | (unsigned int)cl[i];
            gof[s] = gbase[b] + (s - ebase[b]);
        }
    }
    __syncthreads();
    int nval = min(CH, NE - e0);
    for (int s = t; s < nval; s += 256) bedge[gof[s]] = pk[s];
}

// ---------------- per-bucket: degree, dinv, offs, per-node CSR ----------------
__global__ __launch_bounds__(256) void k_bucket(const unsigned int* __restrict__ bedge,
                                                const int* __restrict__ boffs,
                                                int* __restrict__ offs,
                                                float* __restrict__ dinv,
                                                int* __restrict__ scol) {
    __shared__ int cnt[RPB];
    __shared__ int loff[RPB];
    __shared__ int wtot[2];
    __shared__ unsigned int ld[CAP];
    __shared__ int buf[CAP];

    int b = blockIdx.x, t = threadIdx.x;
    int beg = boffs[b], end = boffs[b + 1];
    int m = end - beg;
    int nbase = b << RSH;

    if (t < RPB) cnt[t] = 0;
    __syncthreads();

    if (m <= CAP) {
        for (int i = t; i < m; i += 256) {
            unsigned int mm = bedge[beg + i];
            ld[i] = mm;
            atomicAdd(&cnt[mm >> 17], 1);
        }
        __syncthreads();
        // exclusive scan of 128 counters (2 waves via shfl)
        if (t < RPB) {
            int v = cnt[t];
            int x = v;
#pragma unroll
            for (int d = 1; d < 64; d <<= 1) {
                int y = __shfl_up(x, d);
                if ((t & 63) >= d) x += y;
            }
            if ((t & 63) == 63) wtot[t >> 6] = x;
            loff[t] = x - v;
        }
        __syncthreads();
        if (t >= 64 && t < RPB) loff[t] += wtot[0];
        __syncthreads();
        // write offs + dinv (coalesced)
        if (t < RPB) {
            int n = nbase + t;
            if (n < NN) {
                offs[n] = beg + loff[t];
                dinv[n] = rsqrtf((float)(cnt[t] + 1));
            }
        }
        if (b == NB - 1 && t == 0) offs[NN] = NE;
        // scatter within LDS
        if (t < RPB) cnt[t] = loff[t];  // cursors
        __syncthreads();
        for (int i = t; i < m; i += 256) {
            unsigned int mm = ld[i];
            int s = atomicAdd(&cnt[mm >> 17], 1);
            buf[s] = (int)(mm & 0x1FFFFu);
        }
        __syncthreads();
        for (int i = t; i < m; i += 256) scol[beg + i] = buf[i];
    } else {  // fallback (never expected at these sizes)
        for (int i = t; i < m; i += 256)
            atomicAdd(&cnt[bedge[beg + i] >> 17], 1);
        __syncthreads();
        if (t < RPB) {
            int v = cnt[t];
            int x = v;
#pragma unroll
            for (int d = 1; d < 64; d <<= 1) {
                int y = __shfl_up(x, d);
                if ((t & 63) >= d) x += y;
            }
            if ((t & 63) == 63) wtot[t >> 6] = x;
            loff[t] = x - v;
        }
        __syncthreads();
        if (t >= 64 && t < RPB) loff[t] += wtot[0];
        __syncthreads();
        if (t < RPB) {
            int n = nbase + t;
            if (n < NN) {
                offs[n] = beg + loff[t];
                dinv[n] = rsqrtf((float)(cnt[t] + 1));
            }
        }
        if (b == NB - 1 && t == 0) offs[NN] = NE;
        if (t < RPB) cnt[t] = loff[t];
        __syncthreads();
        for (int i = t; i < m; i += 256) {
            unsigned int mm = bedge[beg + i];
            int s = atomicAdd(&cnt[mm >> 17], 1);
            scol[beg + s] = (int)(mm & 0x1FFFFu);
        }
    }
}

// ---------------- GEMM1: h1s = fp16( dinv[n] * (feat @ W1) ) ----------------
__global__ __launch_bounds__(256) void k_gemm1(const float* __restrict__ feat,
                                               const float* __restrict__ W1,
                                               const float* __restrict__ dinv,
                                               __half* __restrict__ h1s) {
    __shared__ float sW[IN_DIM * HID];
    __shared__ float sF[16][IN_DIM];
    int t = threadIdx.x;

    const float4* W4  = (const float4*)W1;
    float4*       sW4 = (float4*)sW;
#pragma unroll
    for (int i = 0; i < 8; ++i) sW4[t + i * 256] = W4[t + i * 256];

    int n0 = blockIdx.x * 16;
    const float4* F4  = (const float4*)(feat + (size_t)n0 * IN_DIM);
    float4*       sF4 = (float4*)&sF[0][0];
    sF4[t]       = F4[t];
    sF4[t + 256] = F4[t + 256];
    __syncthreads();

    int c = t & 63;
    int g = t >> 6;
    float acc[4] = {0.f, 0.f, 0.f, 0.f};
    for (int k = 0; k < IN_DIM; ++k) {
        float w = sW[k * HID + c];
#pragma unroll
        for (int i = 0; i < 4; ++i) acc[i] += sF[g * 4 + i][k] * w;
    }
#pragma unroll
    for (int i = 0; i < 4; ++i) {
        int n = n0 + g * 4 + i;
        h1s[(size_t)n * HID + c] = __float2half(acc[i] * dinv[n]);
    }
}

// ---------------- fused: agg1(gather) + b1 + relu + @W2 -> h2s (pre-scaled) ----------------
__global__ __launch_bounds__(256) void k_agg1(const int* __restrict__ offs,
                                              const int* __restrict__ scol,
                                              const float* __restrict__ dinv,
                                              const __half* __restrict__ h1s,
                                              const float* __restrict__ b1,
                                              const float* __restrict__ W2,
                                              float* __restrict__ h2s) {
    int n    = blockIdx.x * 4 + (threadIdx.x >> 6);
    int lane = threadIdx.x & 63;
    if (n >= NN) return;
    int beg = offs[n], end = offs[n + 1];
    float acc = 0.f;
    int k = beg;
    for (; k + 3 < end; k += 4) {
        int c0 = scol[k], c1 = scol[k + 1], c2 = scol[k + 2], c3 = scol[k + 3];
        float v0 = __half2float(h1s[(size_t)c0 * HID + lane]);
        float v1 = __half2float(h1s[(size_t)c1 * HID + lane]);
        float v2 = __half2float(h1s[(size_t)c2 * HID + lane]);
        float v3 = __half2float(h1s[(size_t)c3 * HID + lane]);
        acc += (v0 + v1) + (v2 + v3);
    }
    for (; k < end; ++k)
        acc += __half2float(h1s[(size_t)scol[k] * HID + lane]);

    float di = dinv[n];
    acc = di * (acc + __half2float(h1s[(size_t)n * HID + lane]));  // + self loop
    acc += b1[lane];
    acc = fmaxf(acc, 0.f);
    float p0 = acc * W2[lane * 2 + 0];
    float p1 = acc * W2[lane * 2 + 1];
#pragma unroll
    for (int d = 32; d >= 1; d >>= 1) {
        p0 += __shfl_xor(p0, d);
        p1 += __shfl_xor(p1, d);
    }
    if (lane == 0) {
        h2s[(size_t)n * 2 + 0] = di * p0;
        h2s[(size_t)n * 2 + 1] = di * p1;
    }
}

// ---------------- fused: emb = dinv[n]*(gather(h2s)+self) + b2 ----------------
__global__ __launch_bounds__(256) void k_agg2(const int* __restrict__ offs,
                                              const int* __restrict__ scol,
                                              const float* __restrict__ dinv,
                                              const float* __restrict__ h2s,
                                              const float* __restrict__ b2,
                                              float* __restrict__ emb) {
    int n    = blockIdx.x * 4 + (threadIdx.x >> 6);
    int lane = threadIdx.x & 63;
    if (n >= NN) return;
    int beg = offs[n], end = offs[n + 1];
    float e0 = 0.f, e1 = 0.f;
    const float2* h22 = (const float2*)h2s;
    for (int k = beg + lane; k < end; k += 64) {
        float2 v = h22[scol[k]];
        e0 += v.x;
        e1 += v.y;
    }
#pragma unroll
    for (int d = 32; d >= 1; d >>= 1) {
        e0 += __shfl_xor(e0, d);
        e1 += __shfl_xor(e1, d);
    }
    if (lane == 0) {
        float di = dinv[n];
        float2 self = h22[n];
        emb[(size_t)n * 2 + 0] = di * (e0 + self.x) + b2[0];
        emb[(size_t)n * 2 + 1] = di * (e1 + self.y) + b2[1];
    }
}

// ---------------- q = 1/(1 + alpha * d^(2*beta)) ----------------
__global__ void k_q(const int* __restrict__ pr, const int* __restrict__ pc,
                    const int* __restrict__ nr, const int* __restrict__ nc,
                    const float* __restrict__ emb, float* __restrict__ q) {
    int e = blockIdx.x * blockDim.x + threadIdx.x;
    if (e >= 2 * NE) return;
    int a, b;
    if (e < NE) { a = pr[e]; b = pc[e]; }
    else        { a = nr[e - NE]; b = nc[e - NE]; }
    const float2* e2 = (const float2*)emb;
    float2 A = e2[a], B = e2[b];
    float dx = A.x - B.x, dy = A.y - B.y;
    float d = sqrtf(dx * dx + dy * dy + 1e-12f);
    float p = exp2f(2.0f * BETA * log2f(d));
    q[e] = 1.0f / (1.0f + ALPHA * p);
}

extern "C" void kernel_launch(void* const* d_in, const int* in_sizes, int n_in,
                              void* d_out, int out_size, void* d_ws, size_t ws_size,
                              hipStream_t stream) {
    const float* feat = (const float*)d_in[0];
    const float* W1   = (const float*)d_in[1];
    const float* b1   = (const float*)d_in[2];
    const float* W2   = (const float*)d_in[3];
    const float* b2   = (const float*)d_in[4];
    const int*   ei   = (const int*)d_in[5];
    const int*   nrw  = (const int*)d_in[6];
    const int*   ncl  = (const int*)d_in[7];
    const int* row = ei;
    const int* col = ei + NE;

    char* cur = (char*)d_ws;
    auto alloc = [&](size_t bytes) -> char* {
        char* p = cur;
        cur += (bytes + 255) & ~(size_t)255;
        return p;
    };
    int*          bhist = (int*)alloc(sizeof(int) * NB);
    int*          boffs = (int*)alloc(sizeof(int) * (NB + 1));
    int*          bcur  = (int*)alloc(sizeof(int) * NB);
    int*          offs  = (int*)alloc(sizeof(int) * (NN + 1));
    float*        dinv  = (float*)alloc(sizeof(float) * NN);
    unsigned int* bedge = (unsigned int*)alloc(sizeof(unsigned int) * NE);
    int*          scol  = (int*)alloc(sizeof(int) * NE);
    float*        h2s   = (float*)alloc(sizeof(float) * (size_t)NN * 2);
    __half*       h1s   = (__half*)alloc(sizeof(__half) * (size_t)NN * HID);

    float* emb = (float*)d_out;
    float* q   = (float*)d_out + (size_t)NN * 2;

    hipError_t _e = hipMemsetAsync(bhist, 0, sizeof(int) * NB, stream);
    (void)_e;

    k_bhist  <<<NCH, 256, 0, stream>>>(row, bhist);
    k_bscan  <<<1, 256, 0, stream>>>(bhist, boffs, bcur);
    k_binfill<<<NCH, 256, 0, stream>>>(row, col, bcur, bedge);
    k_bucket <<<NB, 256, 0, stream>>>(bedge, boffs, offs, dinv, scol);

    k_gemm1<<<NN / 16, 256, 0, stream>>>(feat, W1, dinv, h1s);

    k_agg1<<<(NN + 3) / 4, 256, 0, stream>>>(offs, scol, dinv, h1s, b1, W2, h2s);
    k_agg2<<<(NN + 3) / 4, 256, 0, stream>>>(offs, scol, dinv, h2s, b2, emb);

    k_q<<<(2 * NE + 255) / 256, 256, 0, stream>>>(row, col, nrw, ncl, emb, q);
}

// Round 8
// 107.798 us; speedup vs baseline: 5.0973x; 1.1902x over previous
//
#include <hip/hip_runtime.h>
#include <hip/hip_fp16.h>
#include <math.h>

constexpr int   NN     = 50000;   // nodes
constexpr int   IN_DIM = 128;
constexpr int   HID    = 64;
constexpr int   NE     = 800000;  // edges
constexpr float ALPHA  = 0.1520f;
constexpr float BETA   = 0.7900f;

constexpr int RSH = 7;                      // rows per bucket = 128
constexpr int RPB = 1 << RSH;
constexpr int NB  = (NN + RPB - 1) / RPB;   // 391 buckets
constexpr int NBP = 512;                    // padded width
constexpr int CH  = 4096;                   // edges per chunk block
constexpr int NCH = (NE + CH - 1) / CH;     // 196
constexpr int CAP = 4096;                   // per-bucket LDS edge capacity

// ---------------- per-chunk bucket histogram -> bpart[b][chunk] (no memset!) ----------------
__global__ __launch_bounds__(256) void k_bhist(const int* __restrict__ row,
                                               int* __restrict__ bpart) {
    __shared__ int h[NBP];
    int t = threadIdx.x;
    for (int i = t; i < NBP; i += 256) h[i] = 0;
    __syncthreads();
    int e0 = blockIdx.x * CH;
#pragma unroll
    for (int i = 0; i < 16; ++i) {
        int e = e0 + i * 256 + t;
        if (e < NE) atomicAdd(&h[row[e] >> RSH], 1);
    }
    __syncthreads();
    for (int b = t; b < NB; b += 256) bpart[b * NCH + blockIdx.x] = h[b];
}

// ---------------- column-sum bpart -> bhist ----------------
__global__ void k_bsum(const int* __restrict__ bpart, int* __restrict__ bhist) {
    int b = blockIdx.x;
    int v = 0;
    for (int i = threadIdx.x; i < NCH; i += 64) v += bpart[b * NCH + i];
#pragma unroll
    for (int d = 32; d >= 1; d >>= 1) v += __shfl_xor(v, d);
    if (threadIdx.x == 0) bhist[b] = v;
}

// ---------------- exclusive scan of bucket counts ----------------
__global__ void k_bscan(const int* __restrict__ bhist, int* __restrict__ boffs,
                        int* __restrict__ bcur) {
    __shared__ int s[NBP];
    int t = threadIdx.x;  // 256
    s[t]       = (t < NB) ? bhist[t] : 0;
    s[t + 256] = (t + 256 < NB) ? bhist[t + 256] : 0;
    __syncthreads();
    for (int d = 1; d < NBP; d <<= 1) {
        int v0 = (t >= d) ? s[t - d] : 0;
        int v1 = (t + 256 >= d) ? s[t + 256 - d] : 0;
        __syncthreads();
        s[t] += v0;
        s[t + 256] += v1;
        __syncthreads();
    }
    if (t < NB)       { int e = s[t] - bhist[t];             boffs[t] = e;       bcur[t] = e; }
    if (t + 256 < NB) { int e = s[t + 256] - bhist[t + 256]; boffs[t + 256] = e; bcur[t + 256] = e; }
    if (t == 0) boffs[NB] = NE;
}

// ---------------- bucket-sort edges into packed words, coalesced runs ----------------
__global__ __launch_bounds__(256) void k_binfill(const int* __restrict__ row,
                                                 const int* __restrict__ col,
                                                 int* __restrict__ bcur,
                                                 unsigned int* __restrict__ bedge) {
    __shared__ int hist[NBP];
    __shared__ int scn[NBP];
    __shared__ int ebase[NB];
    __shared__ int gbase[NB];
    __shared__ int lcur[NB];
    __shared__ unsigned int pk[CH];
    __shared__ int gof[CH];

    int t = threadIdx.x;
    int e0 = blockIdx.x * CH;
    int rw[16], cl[16];
#pragma unroll
    for (int i = 0; i < 16; ++i) {
        int e = e0 + i * 256 + t;
        if (e < NE) { rw[i] = row[e]; cl[i] = col[e]; } else rw[i] = -1;
    }
    for (int i = t; i < NBP; i += 256) hist[i] = 0;
    __syncthreads();
#pragma unroll
    for (int i = 0; i < 16; ++i)
        if (rw[i] >= 0) atomicAdd(&hist[rw[i] >> RSH], 1);
    __syncthreads();
    scn[t] = hist[t];
    scn[t + 256] = hist[t + 256];
    __syncthreads();
    for (int d = 1; d < NBP; d <<= 1) {
        int v0 = (t >= d) ? scn[t - d] : 0;
        int v1 = (t + 256 >= d) ? scn[t + 256 - d] : 0;
        __syncthreads();
        scn[t] += v0;
        scn[t + 256] += v1;
        __syncthreads();
    }
    for (int b = t; b < NB; b += 256) {
        int h  = hist[b];
        int eb = scn[b] - h;
        ebase[b] = eb;
        lcur[b]  = eb;
        gbase[b] = h ? atomicAdd(&bcur[b], h) : 0;
    }
    __syncthreads();
#pragma unroll
    for (int i = 0; i < 16; ++i) {
        if (rw[i] >= 0) {
            int b = rw[i] >> RSH;
            int s = atomicAdd(&lcur[b], 1);
            pk[s]  = ((unsigned int)(rw[i] & (RPB - 1)) << 17) | (unsigned int)cl[i];
            gof[s] = gbase[b] + (s - ebase[b]);
        }
    }
    __syncthreads();
    int nval = min(CH, NE - e0);
    for (int s = t; s < nval; s += 256) bedge[gof[s]] = pk[s];
}

// ---------------- per-bucket: degree, dinv, offs, per-node CSR ----------------
__global__ __launch_bounds__(256) void k_bucket(const unsigned int* __restrict__ bedge,
                                                const int* __restrict__ boffs,
                                                int* __restrict__ offs,
                                                float* __restrict__ dinv,
                                                int* __restrict__ scol) {
    __shared__ int cnt[RPB];
    __shared__ int loff[RPB];
    __shared__ int wtot[2];
    __shared__ unsigned int ld[CAP];
    __shared__ int buf[CAP];

    int b = blockIdx.x, t = threadIdx.x;
    int beg = boffs[b], end = boffs[b + 1];
    int m = end - beg;
    int nbase = b << RSH;

    if (t < RPB) cnt[t] = 0;
    __syncthreads();

    if (m <= CAP) {
        for (int i = t; i < m; i += 256) {
            unsigned int mm = bedge[beg + i];
            ld[i] = mm;
            atomicAdd(&cnt[mm >> 17], 1);
        }
        __syncthreads();
        if (t < RPB) {
            int v = cnt[t];
            int x = v;
#pragma unroll
            for (int d = 1; d < 64; d <<= 1) {
                int y = __shfl_up(x, d);
                if ((t & 63) >= d) x += y;
            }
            if ((t & 63) == 63) wtot[t >> 6] = x;
            loff[t] = x - v;
        }
        __syncthreads();
        if (t >= 64 && t < RPB) loff[t] += wtot[0];
        __syncthreads();
        if (t < RPB) {
            int n = nbase + t;
            if (n < NN) {
                offs[n] = beg + loff[t];
                dinv[n] = rsqrtf((float)(cnt[t] + 1));
            }
        }
        if (b == NB - 1 && t == 0) offs[NN] = NE;
        if (t < RPB) cnt[t] = loff[t];  // cursors
        __syncthreads();
        for (int i = t; i < m; i += 256) {
            unsigned int mm = ld[i];
            int s = atomicAdd(&cnt[mm >> 17], 1);
            buf[s] = (int)(mm & 0x1FFFFu);
        }
        __syncthreads();
        for (int i = t; i < m; i += 256) scol[beg + i] = buf[i];
    } else {  // fallback (never expected)
        for (int i = t; i < m; i += 256)
            atomicAdd(&cnt[bedge[beg + i] >> 17], 1);
        __syncthreads();
        if (t < RPB) {
            int v = cnt[t];
            int x = v;
#pragma unroll
            for (int d = 1; d < 64; d <<= 1) {
                int y = __shfl_up(x, d);
                if ((t & 63) >= d) x += y;
            }
            if ((t & 63) == 63) wtot[t >> 6] = x;
            loff[t] = x - v;
        }
        __syncthreads();
        if (t >= 64 && t < RPB) loff[t] += wtot[0];
        __syncthreads();
        if (t < RPB) {
            int n = nbase + t;
            if (n < NN) {
                offs[n] = beg + loff[t];
                dinv[n] = rsqrtf((float)(cnt[t] + 1));
            }
        }
        if (b == NB - 1 && t == 0) offs[NN] = NE;
        if (t < RPB) cnt[t] = loff[t];
        __syncthreads();
        for (int i = t; i < m; i += 256) {
            unsigned int mm = bedge[beg + i];
            int s = atomicAdd(&cnt[mm >> 17], 1);
            scol[beg + s] = (int)(mm & 0x1FFFFu);
        }
    }
}

// ---------------- GEMM1: h1s = fp16( dinv[n] * (feat @ W1) ) ----------------
__global__ __launch_bounds__(256) void k_gemm1(const float* __restrict__ feat,
                                               const float* __restrict__ W1,
                                               const float* __restrict__ dinv,
                                               __half* __restrict__ h1s) {
    __shared__ float sW[IN_DIM * HID];
    __shared__ float sF[16][IN_DIM];
    int t = threadIdx.x;

    const float4* W4  = (const float4*)W1;
    float4*       sW4 = (float4*)sW;
#pragma unroll
    for (int i = 0; i < 8; ++i) sW4[t + i * 256] = W4[t + i * 256];

    int n0 = blockIdx.x * 16;
    const float4* F4  = (const float4*)(feat + (size_t)n0 * IN_DIM);
    float4*       sF4 = (float4*)&sF[0][0];
    sF4[t]       = F4[t];
    sF4[t + 256] = F4[t + 256];
    __syncthreads();

    int c = t & 63;
    int g = t >> 6;
    float acc[4] = {0.f, 0.f, 0.f, 0.f};
    for (int k = 0; k < IN_DIM; ++k) {
        float w = sW[k * HID + c];
#pragma unroll
        for (int i = 0; i < 4; ++i) acc[i] += sF[g * 4 + i][k] * w;
    }
#pragma unroll
    for (int i = 0; i < 4; ++i) {
        int n = n0 + g * 4 + i;
        h1s[(size_t)n * HID + c] = __float2half(acc[i] * dinv[n]);
    }
}

// ---------------- fused agg1: wave/node, lane=(edge-slot, ch-quad), uint2 gathers ----------------
__global__ __launch_bounds__(256) void k_agg1(const int* __restrict__ offs,
                                              const int* __restrict__ scol,
                                              const float* __restrict__ dinv,
                                              const __half* __restrict__ h1s,
                                              const float* __restrict__ b1,
                                              const float* __restrict__ W2,
                                              float* __restrict__ h2s) {
    int n    = blockIdx.x * 4 + (threadIdx.x >> 6);
    int lane = threadIdx.x & 63;
    if (n >= NN) return;
    int g  = lane >> 4;      // edge slot 0..3
    int cq = lane & 15;      // channel quad: channels 4cq..4cq+3
    int beg = offs[n], end = offs[n + 1];

    const uint2* H = (const uint2*)h1s;  // 16 uint2 per 64-ch row
    float a0 = 0.f, a1 = 0.f, a2 = 0.f, a3 = 0.f;
    int k = beg + g;
    for (; k + 4 < end; k += 8) {
        uint2 va = H[(size_t)scol[k] * 16 + cq];
        uint2 vb = H[(size_t)scol[k + 4] * 16 + cq];
        float2 fa0 = __half22float2(*(__half2*)&va.x);
        float2 fa1 = __half22float2(*(__half2*)&va.y);
        float2 fb0 = __half22float2(*(__half2*)&vb.x);
        float2 fb1 = __half22float2(*(__half2*)&vb.y);
        a0 += fa0.x + fb0.x;
        a1 += fa0.y + fb0.y;
        a2 += fa1.x + fb1.x;
        a3 += fa1.y + fb1.y;
    }
    if (k < end) {
        uint2 va = H[(size_t)scol[k] * 16 + cq];
        float2 fa0 = __half22float2(*(__half2*)&va.x);
        float2 fa1 = __half22float2(*(__half2*)&va.y);
        a0 += fa0.x; a1 += fa0.y; a2 += fa1.x; a3 += fa1.y;
    }
    // sum over the 4 edge slots
    a0 += __shfl_xor(a0, 16); a0 += __shfl_xor(a0, 32);
    a1 += __shfl_xor(a1, 16); a1 += __shfl_xor(a1, 32);
    a2 += __shfl_xor(a2, 16); a2 += __shfl_xor(a2, 32);
    a3 += __shfl_xor(a3, 16); a3 += __shfl_xor(a3, 32);

    // self loop + dinv[row] scale + bias + relu
    uint2 sv = H[(size_t)n * 16 + cq];
    float2 s0 = __half22float2(*(__half2*)&sv.x);
    float2 s1 = __half22float2(*(__half2*)&sv.y);
    float di = dinv[n];
    float4 b14 = ((const float4*)b1)[cq];
    a0 = fmaxf(di * (a0 + s0.x) + b14.x, 0.f);
    a1 = fmaxf(di * (a1 + s0.y) + b14.y, 0.f);
    a2 = fmaxf(di * (a2 + s1.x) + b14.z, 0.f);
    a3 = fmaxf(di * (a3 + s1.y) + b14.w, 0.f);

    // @W2 (64x2): rows 4cq..4cq+3
    float4 w01 = ((const float4*)W2)[cq * 2];      // rows 4cq, 4cq+1
    float4 w23 = ((const float4*)W2)[cq * 2 + 1];  // rows 4cq+2, 4cq+3
    float p0 = a0 * w01.x + a1 * w01.z + a2 * w23.x + a3 * w23.z;
    float p1 = a0 * w01.y + a1 * w01.w + a2 * w23.y + a3 * w23.w;
#pragma unroll
    for (int d = 8; d >= 1; d >>= 1) {
        p0 += __shfl_xor(p0, d);
        p1 += __shfl_xor(p1, d);
    }
    if (lane == 0) {
        h2s[(size_t)n * 2 + 0] = di * p0;
        h2s[(size_t)n * 2 + 1] = di * p1;
    }
}

// ---------------- fused agg2: 4 nodes per wave, 16 lanes each ----------------
__global__ __launch_bounds__(256) void k_agg2(const int* __restrict__ offs,
                                              const int* __restrict__ scol,
                                              const float* __restrict__ dinv,
                                              const float* __restrict__ h2s,
                                              const float* __restrict__ b2,
                                              float* __restrict__ emb) {
    int wid  = threadIdx.x >> 6;
    int lane = threadIdx.x & 63;
    int n = blockIdx.x * 16 + wid * 4 + (lane >> 4);
    int e = lane & 15;
    const float2* h22 = (const float2*)h2s;
    float e0 = 0.f, e1 = 0.f;
    int beg = 0, end = 0;
    if (n < NN) { beg = offs[n]; end = offs[n + 1]; }
    for (int k = beg + e; k < end; k += 16) {
        float2 v = h22[scol[k]];
        e0 += v.x;
        e1 += v.y;
    }
#pragma unroll
    for (int d = 8; d >= 1; d >>= 1) {
        e0 += __shfl_xor(e0, d);
        e1 += __shfl_xor(e1, d);
    }
    if (e == 0 && n < NN) {
        float di = dinv[n];
        float2 self = h22[n];
        emb[(size_t)n * 2 + 0] = di * (e0 + self.x) + b2[0];
        emb[(size_t)n * 2 + 1] = di * (e1 + self.y) + b2[1];
    }
}

// ---------------- q = 1/(1 + alpha * d^(2*beta)) ----------------
__global__ void k_q(const int* __restrict__ pr, const int* __restrict__ pc,
                    const int* __restrict__ nr, const int* __restrict__ nc,
                    const float* __restrict__ emb, float* __restrict__ q) {
    int e = blockIdx.x * blockDim.x + threadIdx.x;
    if (e >= 2 * NE) return;
    int a, b;
    if (e < NE) { a = pr[e]; b = pc[e]; }
    else        { a = nr[e - NE]; b = nc[e - NE]; }
    const float2* e2 = (const float2*)emb;
    float2 A = e2[a], B = e2[b];
    float dx = A.x - B.x, dy = A.y - B.y;
    float d = sqrtf(dx * dx + dy * dy + 1e-12f);
    float p = exp2f(2.0f * BETA * log2f(d));
    q[e] = 1.0f / (1.0f + ALPHA * p);
}

extern "C" void kernel_launch(void* const* d_in, const int* in_sizes, int n_in,
                              void* d_out, int out_size, void* d_ws, size_t ws_size,
                              hipStream_t stream) {
    const float* feat = (const float*)d_in[0];
    const float* W1   = (const float*)d_in[1];
    const float* b1   = (const float*)d_in[2];
    const float* W2   = (const float*)d_in[3];
    const float* b2   = (const float*)d_in[4];
    const int*   ei   = (const int*)d_in[5];
    const int*   nrw  = (const int*)d_in[6];
    const int*   ncl  = (const int*)d_in[7];
    const int* row = ei;
    const int* col = ei + NE;

    char* cur = (char*)d_ws;
    auto alloc = [&](size_t bytes) -> char* {
        char* p = cur;
        cur += (bytes + 255) & ~(size_t)255;
        return p;
    };
    int*          bpart = (int*)alloc(sizeof(int) * (size_t)NB * NCH);
    int*          bhist = (int*)alloc(sizeof(int) * NB);
    int*          boffs = (int*)alloc(sizeof(int) * (NB + 1));
    int*          bcur  = (int*)alloc(sizeof(int) * NB);
    int*          offs  = (int*)alloc(sizeof(int) * (NN + 1));
    float*        dinv  = (float*)alloc(sizeof(float) * NN);
    unsigned int* bedge = (unsigned int*)alloc(sizeof(unsigned int) * NE);
    int*          scol  = (int*)alloc(sizeof(int) * NE);
    float*        h2s   = (float*)alloc(sizeof(float) * (size_t)NN * 2);
    __half*       h1s   = (__half*)alloc(sizeof(__half) * (size_t)NN * HID);

    float* emb = (float*)d_out;
    float* q   = (float*)d_out + (size_t)NN * 2;

    k_bhist  <<<NCH, 256, 0, stream>>>(row, bpart);
    k_bsum   <<<NB, 64, 0, stream>>>(bpart, bhist);
    k_bscan  <<<1, 256, 0, stream>>>(bhist, boffs, bcur);
    k_binfill<<<NCH, 256, 0, stream>>>(row, col, bcur, bedge);
    k_bucket <<<NB, 256, 0, stream>>>(bedge, boffs, offs, dinv, scol);

    k_gemm1<<<NN / 16, 256, 0, stream>>>(feat, W1, dinv, h1s);

    k_agg1<<<(NN + 3) / 4, 256, 0, stream>>>(offs, scol, dinv, h1s, b1, W2, h2s);
    k_agg2<<<(NN + 15) / 16, 256, 0, stream>>>(offs, scol, dinv, h2s, b2, emb);

    k_q<<<(2 * NE + 255) / 256, 256, 0, stream>>>(row, col, nrw, ncl, emb, q);
}